// Round 6
// baseline (509.691 us; speedup 1.0000x reference)
//
#include <hip/hip_runtime.h>

// Problem constants (static in the reference)
#define NN 1024
#define MM 64
#define BB 8
#define EE 63456   // sum_i min(i,64) = 2016 + 960*64

// ws float layout
#define WS_WN    0        // Wn_eff 192x64 fp32 (rows: src 0..63 | dst 64..127 | edge 128..191)
#define WS_WE    12288    // We_eff 128x64 fp32 (rows: src 0..63 | edge 64..127)
#define WS_BN    20480    // bn_eff 64 fp32
#define WS_BE    20544    // be_eff 64 fp32
#define WS_B2H   20608    // B2 hi fragments: [4 nt][8 ks][64 lane][8 e] ushort (16384 us)
#define WS_B2L   28800    // B2 lo
#define WS_B5H   36992    // B5 hi: [2 nt][8 ks][64 lane][8 e] ushort (8192 us)
#define WS_B5L   41088    // B5 lo
#define WS_TOTAL 45184    // floats (~181 KB)

using short8 = __attribute__((ext_vector_type(8))) short;
using f32x16 = __attribute__((ext_vector_type(16))) float;

__device__ __forceinline__ unsigned bf16_rne(float x) {
    unsigned u = __float_as_uint(x);
    return (u + 0x7fffu + ((u >> 16) & 1u)) >> 16;
}

// Prep 1: collapse the inner linear pairs (no inner ReLU in the reference!).
__global__ __launch_bounds__(64)
void collapse_kernel(
    const float* __restrict__ Wn1, const float* __restrict__ bn1,
    const float* __restrict__ Wn2, const float* __restrict__ bn2,
    const float* __restrict__ We1, const float* __restrict__ be1,
    const float* __restrict__ We2, const float* __restrict__ be2,
    float* __restrict__ ws)
{
    const int r = blockIdx.x;
    const int n = threadIdx.x;
    if (r < 192) {                      // Wn_eff row r
        float acc = 0.f;
#pragma unroll 16
        for (int t = 0; t < 128; ++t) acc += Wn1[r * 128 + t] * Wn2[t * 64 + n];
        ws[WS_WN + r * 64 + n] = acc;
    } else if (r < 320) {               // We_eff row r-192
        const int rr = r - 192;
        float acc = 0.f;
#pragma unroll 16
        for (int t = 0; t < 128; ++t) acc += We1[rr * 128 + t] * We2[t * 64 + n];
        ws[WS_WE + rr * 64 + n] = acc;
    } else if (r == 320) {              // bn_eff
        float acc = bn2[n];
#pragma unroll 16
        for (int t = 0; t < 128; ++t) acc += bn1[t] * Wn2[t * 64 + n];
        ws[WS_BN + n] = acc;
    } else {                            // be_eff
        float acc = be2[n];
#pragma unroll 16
        for (int t = 0; t < 128; ++t) acc += be1[t] * We2[t * 64 + n];
        ws[WS_BE + n] = acc;
    }
}

// Prep 2: pack split-bf16 MFMA B-fragments (pure reformat).
// B-fragment (32x32x16): lane l holds n = nt*32+(l&31), k = ks*16+(l>>5)*8+e.
__global__ void pack_kernel(const float* __restrict__ Wef, float* __restrict__ ws)
{
    int idx = blockIdx.x * 256 + threadIdx.x;
    if (idx >= 24576) return;
    float v; int pos, offh, offl;
    if (idx < 16384) {
        int e = idx & 7, l = (idx >> 3) & 63, ks = (idx >> 9) & 7, nt = idx >> 12;
        int k = ks * 16 + (l >> 5) * 8 + e;
        int n = nt * 32 + (l & 31);
        if (n < 64) {
            int r = (k < 64) ? k : (64 + k);   // src rows 0..63 ; edge rows 128..191
            v = ws[WS_WN + r * 64 + n];
        } else {
            v = ws[WS_WE + k * 64 + (n - 64)];
        }
        pos = idx; offh = WS_B2H; offl = WS_B2L;
    } else {
        int t2 = idx - 16384;
        int e = t2 & 7, l = (t2 >> 3) & 63, ks = (t2 >> 9) & 7, nt = t2 >> 12;
        int k = ks * 16 + (l >> 5) * 8 + e;
        int n = nt * 32 + (l & 31);
        v = Wef[k * 64 + n];
        pos = t2; offh = WS_B5H; offl = WS_B5L;
    }
    unsigned hh = bf16_rne(v);
    unsigned ll = bf16_rne(v - __uint_as_float(hh << 16));
    ((unsigned short*)(ws + offh))[pos] = (unsigned short)hh;
    ((unsigned short*)(ws + offl))[pos] = (unsigned short)ll;
}

// Main: 256 threads (4 waves) per (b,i); 26KB LDS -> 6 independent blocks/CU.
// Wave wv owns N-slab wv (32 cols) x BOTH 32-row M-tiles: 32 MFMA/wave phase2.
// Waves 0,1 ("n"): accn reduce -> s_agg; phase5 zz = pair@Wef[:64] + in-register
// scan + out_edges stores. Waves 2,3 ("e"): pair_e -> s_pair (own buffer, no
// overlay barrier); phase5 ze = edge@Wef[64:]; publish ze; out_nodes GEMV.
// All B fragments (24 x 16B) prefetched at kernel start and HELD (VGPR budget
// 341 at 6 waves/SIMD). 4 barriers total.
__global__ __launch_bounds__(256, 6)
void main_kernel(const float* __restrict__ nodes,
                 const float* __restrict__ edges,
                 const float* __restrict__ ws,
                 const float* __restrict__ Wnf,   // W_nodes (128x64) fp32
                 const float* __restrict__ bias,  // bias_edges (64) — both outputs use it (ref quirk)
                 float* __restrict__ out)
{
    __shared__ __align__(16) unsigned short s_A[64 * 128];   // 16 KB; f32 ze overlay after B3
    __shared__ __align__(16) unsigned short s_pair[64 * 64]; // 8 KB pair_e (bf16, swizzled)
    __shared__ float s_dd[4 * 64];
    __shared__ float s_agg[64];
    __shared__ float s_dst[64];

    const int tid = threadIdx.x;
    const int bx  = blockIdx.x;
    const int b   = bx >> 10;
    const int i   = bx & 1023;
    const int w   = (i < MM) ? i : MM;
    const long ns_ = (i <= 64) ? ((long)i * (i - 1)) / 2 : 2016L + (long)(i - 64) * 64;

    const int wv = tid >> 6, l = tid & 63, lo5 = l & 31, hi = l >> 5;
    const bool nw = wv < 2;
    const int ntc = nw ? wv : (wv - 2);

    // ---- prefetch ALL B fragments into registers (held; independent of staging) ----
    short8 pbh[8], pbl[8];
    {
        const unsigned short* Bh = (const unsigned short*)(ws + WS_B2H);
        const unsigned short* Bl = (const unsigned short*)(ws + WS_B2L);
#pragma unroll
        for (int ks = 0; ks < 8; ++ks) {
            pbh[ks] = *(const short8*)&Bh[((wv * 8 + ks) * 64 + l) * 8];
            pbl[ks] = *(const short8*)&Bl[((wv * 8 + ks) * 64 + l) * 8];
        }
    }
    short8 qbh[4], qbl[4];
    {
        const unsigned short* Bh = (const unsigned short*)(ws + WS_B5H);
        const unsigned short* Bl = (const unsigned short*)(ws + WS_B5L);
        const int k0 = nw ? 0 : 4;
#pragma unroll
        for (int kk = 0; kk < 4; ++kk) {
            qbh[kk] = *(const short8*)&Bh[((ntc * 8 + k0 + kk) * 64 + l) * 8];
            qbl[kk] = *(const short8*)&Bl[((ntc * 8 + k0 + kk) * 64 + l) * 8];
        }
    }
    const float bnv = nw ? ws[WS_BN + wv * 32 + lo5] : ws[WS_BE + ntc * 32 + lo5];
    const float bsv = bias[ntc * 32 + lo5];

    // ---- stage dst row (fp32) + A = [src||edge] hi-bf16, 16B-unit XOR swizzle ----
    if (tid < 16)
        *(float4*)&s_dst[tid * 4] = ((const float4*)(nodes + ((size_t)b * NN + i) * 64))[tid];
    for (int idx = tid; idx < w * 16; idx += 256) {
        const int row = idx >> 4, q = idx & 15;   // q<8: src unit ; q>=8: edge unit
        const float* src = (q < 8)
            ? (nodes + ((size_t)b * NN + (i - w) + row) * 64 + q * 8)
            : (edges + ((size_t)b * EE + ns_ + row) * 64 + (q - 8) * 8);
        float4 x0 = *(const float4*)src;
        float4 x1 = *(const float4*)(src + 4);
        unsigned h0 = bf16_rne(x0.x), h1 = bf16_rne(x0.y), h2 = bf16_rne(x0.z), h3 = bf16_rne(x0.w);
        unsigned h4 = bf16_rne(x1.x), h5 = bf16_rne(x1.y), h6 = bf16_rne(x1.z), h7 = bf16_rne(x1.w);
        uint4 H;
        H.x = h0 | (h1 << 16); H.y = h2 | (h3 << 16);
        H.z = h4 | (h5 << 16); H.w = h6 | (h7 << 16);
        *(uint4*)&s_A[row * 128 + (q ^ (row & 15)) * 8] = H;
    }
    __syncthreads();                                      // B1

    // ---- dd partials: wave wv covers c in [wv*16, wv*16+16), all 64 f per wave ----
    {
        float a = 0.f;
        const float* wd = ws + WS_WN + 64 * 64;           // dst-row block of Wn_eff
#pragma unroll
        for (int cc = 0; cc < 16; ++cc) {
            const int c = wv * 16 + cc;
            a += s_dst[c] * wd[c * 64 + l];
        }
        s_dd[wv * 64 + l] = a;
    }

    // ---- Phase 2: wave wv = slab wv (cols), both M-tiles; shared B-frag ----
    f32x16 acc0 = {}, acc1 = {};
    const int r0 = lo5, r1 = 32 + lo5;
    {
#pragma unroll
        for (int ks = 0; ks < 8; ++ks) {
            const int u = ks * 2 + hi;
            short8 a0 = *(const short8*)&s_A[r0 * 128 + (u ^ (r0 & 15)) * 8];
            short8 a1 = *(const short8*)&s_A[r1 * 128 + (u ^ (r1 & 15)) * 8];
            acc0 = __builtin_amdgcn_mfma_f32_32x32x16_bf16(a0, pbh[ks], acc0, 0, 0, 0);
            acc0 = __builtin_amdgcn_mfma_f32_32x32x16_bf16(a0, pbl[ks], acc0, 0, 0, 0);
            acc1 = __builtin_amdgcn_mfma_f32_32x32x16_bf16(a1, pbh[ks], acc1, 0, 0, 0);
            acc1 = __builtin_amdgcn_mfma_f32_32x32x16_bf16(a1, pbl[ks], acc1, 0, 0, 0);
        }
    }

    if (!nw) {
        // pair_e = relu(acce + be) -> bf16 -> s_pair (rows >= w zeroed; own buffer)
        const int fp = ntc * 32 + lo5, ufp = fp >> 3, fo = fp & 7;
#pragma unroll
        for (int reg = 0; reg < 16; ++reg) {
            const int rr = (reg & 3) + 8 * (reg >> 2) + 4 * hi;
            {
                float p = (rr < w) ? fmaxf(acc0[reg] + bnv, 0.f) : 0.f;
                s_pair[rr * 64 + ((ufp ^ (rr & 7)) << 3) + fo] = (unsigned short)bf16_rne(p);
            }
            {
                const int j2 = 32 + rr;
                float p = (j2 < w) ? fmaxf(acc1[reg] + bnv, 0.f) : 0.f;
                s_pair[j2 * 64 + ((ufp ^ (j2 & 7)) << 3) + fo] = (unsigned short)bf16_rne(p);
            }
        }
    }
    __syncthreads();                                      // B2 (pair + dd partials ready)

    if (nw) {
        // accn reduce: agg[f] = sum_{j<w} relu(C + dd[f]) over all 64 rows
        const int f = wv * 32 + lo5;
        const float dd = bnv + s_dd[f] + s_dd[64 + f] + s_dd[128 + f] + s_dd[192 + f];
        float sum = 0.f;
#pragma unroll
        for (int reg = 0; reg < 16; ++reg) {
            const int rr = (reg & 3) + 8 * (reg >> 2) + 4 * hi;
            if (rr < w)      sum += fmaxf(acc0[reg] + dd, 0.f);
            if (32 + rr < w) sum += fmaxf(acc1[reg] + dd, 0.f);
        }
        sum += __shfl_xor(sum, 32);
        if (hi == 0) s_agg[f] = sum;
    }

    // ---- Phase 5: n-waves zz = pair@Wef[0:64]; e-waves ze = edge@Wef[64:128] ----
    f32x16 z0 = {}, z1 = {};
    if (nw) {
#pragma unroll
        for (int kk = 0; kk < 4; ++kk) {
            const int ku = kk * 2 + hi;
            short8 a0 = *(const short8*)&s_pair[r0 * 64 + ((ku ^ (r0 & 7)) << 3)];
            short8 a1 = *(const short8*)&s_pair[r1 * 64 + ((ku ^ (r1 & 7)) << 3)];
            z0 = __builtin_amdgcn_mfma_f32_32x32x16_bf16(a0, qbh[kk], z0, 0, 0, 0);
            z0 = __builtin_amdgcn_mfma_f32_32x32x16_bf16(a0, qbl[kk], z0, 0, 0, 0);
            z1 = __builtin_amdgcn_mfma_f32_32x32x16_bf16(a1, qbh[kk], z1, 0, 0, 0);
            z1 = __builtin_amdgcn_mfma_f32_32x32x16_bf16(a1, qbl[kk], z1, 0, 0, 0);
        }
    } else {
#pragma unroll
        for (int kk = 0; kk < 4; ++kk) {
            const int u = (4 + kk) * 2 + hi;
            short8 a0 = *(const short8*)&s_A[r0 * 128 + (u ^ (r0 & 15)) * 8];
            short8 a1 = *(const short8*)&s_A[r1 * 128 + (u ^ (r1 & 15)) * 8];
            z0 = __builtin_amdgcn_mfma_f32_32x32x16_bf16(a0, qbh[kk], z0, 0, 0, 0);
            z0 = __builtin_amdgcn_mfma_f32_32x32x16_bf16(a0, qbl[kk], z0, 0, 0, 0);
            z1 = __builtin_amdgcn_mfma_f32_32x32x16_bf16(a1, qbh[kk], z1, 0, 0, 0);
            z1 = __builtin_amdgcn_mfma_f32_32x32x16_bf16(a1, qbl[kk], z1, 0, 0, 0);
        }
    }
    __syncthreads();                                      // B3 (all phase-5 LDS reads done)

    float* s_ze = (float*)s_A;                            // f32 [64 rows][64 f] overlay
    float pz0[16], pz1[16], base0[4], base1[4], tot0 = 0.f;
    if (nw) {
        // in-register exclusive prefix over all 64 rows of this wave's columns
        float G[4];
#pragma unroll
        for (int g = 0; g < 4; ++g) {
            float a0 = z0[g * 4], a1 = z0[g * 4 + 1], a2 = z0[g * 4 + 2], a3 = z0[g * 4 + 3];
            pz0[g * 4] = 0.f; pz0[g * 4 + 1] = a0; pz0[g * 4 + 2] = a0 + a1; pz0[g * 4 + 3] = a0 + a1 + a2;
            G[g] = a0 + a1 + a2 + a3;
        }
        float run = 0.f;
#pragma unroll
        for (int g = 0; g < 4; ++g) {
            float Gp = __shfl_xor(G[g], 32);
            base0[g] = run + (hi ? Gp : 0.f);
            run += G[g] + Gp;
        }
        tot0 = run;
#pragma unroll
        for (int g = 0; g < 4; ++g) {
            float a0 = z1[g * 4], a1 = z1[g * 4 + 1], a2 = z1[g * 4 + 2], a3 = z1[g * 4 + 3];
            pz1[g * 4] = 0.f; pz1[g * 4 + 1] = a0; pz1[g * 4 + 2] = a0 + a1; pz1[g * 4 + 3] = a0 + a1 + a2;
            G[g] = a0 + a1 + a2 + a3;
        }
        run = 0.f;
#pragma unroll
        for (int g = 0; g < 4; ++g) {
            float Gp = __shfl_xor(G[g], 32);
            base1[g] = run + (hi ? Gp : 0.f);
            run += G[g] + Gp;
        }
    } else {
        // publish ze into freed s_A as fp32 [j][f]
        const int fz = ntc * 32 + lo5;
#pragma unroll
        for (int reg = 0; reg < 16; ++reg) {
            const int rr = (reg & 3) + 8 * (reg >> 2) + 4 * hi;
            s_ze[rr * 64 + fz]        = z0[reg];
            s_ze[(32 + rr) * 64 + fz] = z1[reg];
        }
    }
    __syncthreads();                                      // B4 (ze published)

    if (nw) {
        // out_edges = relu(prefix/max(j,1) + ze + bias)
        const int f = ntc * 32 + lo5;
        float* oute = out + (size_t)BB * NN * 64;         // out_nodes first, then out_edges
#pragma unroll
        for (int reg = 0; reg < 16; ++reg) {
            const int rr = (reg & 3) + 8 * (reg >> 2) + 4 * hi;
            if (rr < w) {
                const float invj = (rr > 0) ? (1.0f / (float)rr) : 1.0f;
                oute[((size_t)b * EE + ns_ + rr) * 64 + f] =
                    fmaxf((base0[reg >> 2] + pz0[reg]) * invj + s_ze[rr * 64 + f] + bsv, 0.f);
            }
            const int j2 = 32 + rr;
            if (j2 < w) {
                const float invj = 1.0f / (float)j2;
                oute[((size_t)b * EE + ns_ + j2) * 64 + f] =
                    fmaxf((tot0 + base1[reg >> 2] + pz1[reg]) * invj + s_ze[j2 * 64 + f] + bsv, 0.f);
            }
        }
    } else {
        // out_nodes GEMV: [agg/max(w,1) || dst] @ W_nodes + bias
        const int f = ntc * 32 + lo5;
        const float invw = 1.0f / (float)((w > 0) ? w : 1);
        float s = 0.f;
#pragma unroll 8
        for (int cc = 0; cc < 32; ++cc) {
            const int c = hi * 32 + cc;
            s += (s_agg[c] * invw) * Wnf[c * 64 + f] + s_dst[c] * Wnf[(64 + c) * 64 + f];
        }
        s += __shfl_xor(s, 32);
        if (hi == 0)
            out[((size_t)b * NN + i) * 64 + f] = fmaxf(s + bsv, 0.f);
    }
}

extern "C" void kernel_launch(void* const* d_in, const int* in_sizes, int n_in,
                              void* d_out, int out_size, void* d_ws, size_t ws_size,
                              hipStream_t stream) {
    const float* nodes = (const float*)d_in[0];
    const float* edges = (const float*)d_in[1];
    const float* Wn1  = (const float*)d_in[2];
    const float* bn1  = (const float*)d_in[3];
    const float* Wn2  = (const float*)d_in[4];
    const float* bn2  = (const float*)d_in[5];
    const float* We1  = (const float*)d_in[6];
    const float* be1  = (const float*)d_in[7];
    const float* We2  = (const float*)d_in[8];
    const float* be2  = (const float*)d_in[9];
    const float* Wnod = (const float*)d_in[10];
    const float* Wedg = (const float*)d_in[11];
    const float* bias = (const float*)d_in[12];
    float* ws = (float*)d_ws;
    float* out = (float*)d_out;

    hipLaunchKernelGGL(collapse_kernel, dim3(322), dim3(64), 0, stream,
                       Wn1, bn1, Wn2, bn2, We1, be1, We2, be2, ws);
    hipLaunchKernelGGL(pack_kernel, dim3(96), dim3(256), 0, stream, Wedg, ws);
    hipLaunchKernelGGL(main_kernel, dim3(BB * NN), dim3(256), 0, stream,
                       nodes, edges, ws, Wnod, bias, out);
}